// Round 2
// baseline (584.889 us; speedup 1.0000x reference)
//
#include <hip/hip_runtime.h>
#include <hip/hip_fp16.h>

// Latency-optimized version.
//
// Structure (unchanged): lane L holds quarter (L&3) of row k*16+(L>>2); all
// global_load/store_dwordx4 are perfectly coalesced (lane i at base+i*16B).
// Quarter-nibbles are OR-combined across each 4-lane quad; all 4 lanes
// redundantly do the fp16 add (VALU is ~90% idle) and extract their own
// quarter of the sum.
//
// Changes vs 195us/dispatch baseline (~3.9 TB/s effective, VALUBusy 9.7%
// => latency-bound, not BW-bound):
//  1. All 8 loads issued back-to-back behind ONE wave-uniform bounds check
//     (old per-k `if(...)return` blocked load hoisting => only 2 outstanding
//     loads/wave). Now 8 outstanding loads/wave = 4x memory-level parallelism.
//  2. __shfl_xor (ds_swizzle, lgkmcnt round-trip) -> DPP quad_perm OR,
//     and A/B nibbles packed in one 32-bit word => 2 DPP ops/iter, no LDS pipe.
//  3. Bits extracted via bit 23 of the f32 pattern (1.0f=0x3F800000) instead
//     of v_cvt_u32_f32 chains.
//  4. Non-temporal stores: output stream (256 MB) doesn't evict inputs from
//     the 256 MiB L3 across bench iterations. (Cast through clang-native
//     ext_vector_type — the builtin rejects HIP_vector_type wrappers.)

typedef float fx4 __attribute__((ext_vector_type(4)));

__global__ __launch_bounds__(256) void spike_fp16_add_kernel(
    const uint4* __restrict__ A, const uint4* __restrict__ B,
    float4* __restrict__ O, int nf4)   // nf4 = total float4 count = nrows*4
{
    const int lane = threadIdx.x & 63;
    const int waveBase = ((blockIdx.x * blockDim.x + threadIdx.x) >> 6) * 256;
    const int q  = lane & 3;
    const int sh = 12 - 4 * q;          // MSB-first nibble position for this quarter

    if (waveBase + 256 <= nf4) {
        // ---- fast path: full 256-float4 wave chunk (always taken for N=4M) ----
        uint4 a[4], b[4];
        #pragma unroll
        for (int k = 0; k < 4; ++k) {
            a[k] = A[waveBase + k * 64 + lane];
            b[k] = B[waveBase + k * 64 + lane];
        }

        #pragma unroll
        for (int k = 0; k < 4; ++k) {
            // bit 23 distinguishes 1.0f (0x3F800000) from 0.0f — no v_cvt needed
            uint32_t na = ((a[k].x >> 20) & 8u) | ((a[k].y >> 21) & 4u) |
                          ((a[k].z >> 22) & 2u) | ((a[k].w >> 23) & 1u);
            uint32_t nb = ((b[k].x >> 20) & 8u) | ((b[k].y >> 21) & 4u) |
                          ((b[k].z >> 22) & 2u) | ((b[k].w >> 23) & 1u);

            // pack A-half (low 16) and B-half (high 16) into one word
            uint32_t w = (na << sh) | (nb << (sh + 16));

            // OR-combine across the 4-lane quad: quad_perm [1,0,3,2] then [2,3,0,1]
            w |= (uint32_t)__builtin_amdgcn_mov_dpp((int)w, 0xB1, 0xF, 0xF, true);
            w |= (uint32_t)__builtin_amdgcn_mov_dpp((int)w, 0x4E, 0xF, 0xF, true);

            // fp16 add via exact fp32 add + RNE convert (bit-exact, 24 >= 2*11+2)
            float fa = __half2float(__ushort_as_half((unsigned short)(w & 0xFFFFu)));
            float fb = __half2float(__ushort_as_half((unsigned short)(w >> 16)));
            uint32_t us = (uint32_t)__half_as_ushort(__float2half_rn(fa + fb));

            // this lane's quarter of the sum, MSB first
            uint32_t ns = (us >> sh) & 0xFu;
            fx4 o;
            o.x = (float)((ns >> 3) & 1u);
            o.y = (float)((ns >> 2) & 1u);
            o.z = (float)((ns >> 1) & 1u);
            o.w = (float)( ns       & 1u);

            __builtin_nontemporal_store(
                o, (fx4*)&O[waveBase + k * 64 + lane]);
        }
    } else {
        // ---- tail path (never taken for the fixed N; kept for generality) ----
        // nf4 is a multiple of 4, so each 4-lane quad passes/fails together
        // and the quad shuffles below stay well-defined.
        #pragma unroll
        for (int k = 0; k < 4; ++k) {
            const int f4 = waveBase + k * 64 + lane;
            if (f4 >= nf4) continue;

            uint4 a = A[f4];
            uint4 b = B[f4];
            uint32_t na = ((a.x >> 20) & 8u) | ((a.y >> 21) & 4u) |
                          ((a.z >> 22) & 2u) | ((a.w >> 23) & 1u);
            uint32_t nb = ((b.x >> 20) & 8u) | ((b.y >> 21) & 4u) |
                          ((b.z >> 22) & 2u) | ((b.w >> 23) & 1u);
            uint32_t w = (na << sh) | (nb << (sh + 16));
            w |= (uint32_t)__shfl_xor((int)w, 1);
            w |= (uint32_t)__shfl_xor((int)w, 2);

            float fa = __half2float(__ushort_as_half((unsigned short)(w & 0xFFFFu)));
            float fb = __half2float(__ushort_as_half((unsigned short)(w >> 16)));
            uint32_t us = (uint32_t)__half_as_ushort(__float2half_rn(fa + fb));

            uint32_t ns = (us >> sh) & 0xFu;
            float4 o;
            o.x = (float)((ns >> 3) & 1u);
            o.y = (float)((ns >> 2) & 1u);
            o.z = (float)((ns >> 1) & 1u);
            o.w = (float)( ns       & 1u);
            O[f4] = o;
        }
    }
}

extern "C" void kernel_launch(void* const* d_in, const int* in_sizes, int n_in,
                              void* d_out, int out_size, void* d_ws, size_t ws_size,
                              hipStream_t stream) {
    const uint4* A = (const uint4*)d_in[0];
    const uint4* B = (const uint4*)d_in[1];
    float4* O = (float4*)d_out;

    int nf4 = in_sizes[0] / 4;          // total float4s per input
    int block = 256;
    // each thread handles 4 float4s -> threads = ceil(nf4/4)
    int threads = (nf4 + 3) / 4;
    int grid = (threads + block - 1) / block;
    spike_fp16_add_kernel<<<grid, block, 0, stream>>>(A, B, O, nf4);
}

// Round 3
// 583.247 us; speedup vs baseline: 1.0028x; 1.0028x over previous
//
#include <hip/hip_runtime.h>
#include <hip/hip_fp16.h>

// Persistent-wave streaming version.
//
// Layout (unchanged): lane L holds quarter (L&3) of a row; every
// global_load/store_dwordx4 is perfectly coalesced (lane i at base+i*16B,
// 1 KiB/wave/instr). Quarter-nibbles OR-combined across each 4-lane quad via
// DPP quad_perm; all 4 lanes redundantly do the fp16 add (VALU ~92% idle)
// and extract their own quarter of the sum.
//
// Changes vs round-2 (205 us/dispatch, occupancy 73%, HBM 2.6 TB/s = 42% of
// copy ceiling -> NOT HBM-bound, NOT wave-latency-bound (4x MLP was null)):
//  1. PERSISTENT grid: 2048 blocks = 8192 waves = exactly 32 waves/CU.
//     Each wave streams 8 contiguous 256-float4 chunks (32 KB runs from A
//     and B). Removes the launch/drain churn of 16384 short-lived blocks
//     that left 27% of wave slots empty (OccupancyPercent 66-75%).
//  2. Reverted non-temporal stores (the only store-path change in round-2's
//     195->205 regression; NT likely hurts TCC write-combining).
//  3. Kept: 8 batched loads per chunk, DPP quad_perm OR, bit-23 extraction.

__global__ __launch_bounds__(256) void spike_fp16_add_kernel(
    const uint4* __restrict__ A, const uint4* __restrict__ B,
    float4* __restrict__ O, int nf4)   // nf4 = total float4 count = nrows*4
{
    const int lane   = threadIdx.x & 63;
    const int wid    = (blockIdx.x * blockDim.x + threadIdx.x) >> 6;
    const int nWaves = (gridDim.x * blockDim.x) >> 6;
    const int q      = lane & 3;
    const int sh     = 12 - 4 * q;      // MSB-first nibble position, this quarter

    const int nChunks = nf4 >> 8;       // 256 float4s per wave-chunk
    const int cpw     = (nChunks + nWaves - 1) / nWaves;
    const int c0      = wid * cpw;
    const int c1      = (c0 + cpw < nChunks) ? c0 + cpw : nChunks;

    for (int c = c0; c < c1; ++c) {
        const int base = (c << 8) + lane;

        // ---- all 8 loads issued back-to-back (8 outstanding / wave) ----
        uint4 a0 = A[base      ], a1 = A[base +  64],
              a2 = A[base + 128], a3 = A[base + 192];
        uint4 b0 = B[base      ], b1 = B[base +  64],
              b2 = B[base + 128], b3 = B[base + 192];

        uint4 av[4] = {a0, a1, a2, a3};
        uint4 bv[4] = {b0, b1, b2, b3};

        #pragma unroll
        for (int k = 0; k < 4; ++k) {
            // bit 23 distinguishes 1.0f (0x3F800000) from 0.0f — no v_cvt
            uint32_t na = ((av[k].x >> 20) & 8u) | ((av[k].y >> 21) & 4u) |
                          ((av[k].z >> 22) & 2u) | ((av[k].w >> 23) & 1u);
            uint32_t nb = ((bv[k].x >> 20) & 8u) | ((bv[k].y >> 21) & 4u) |
                          ((bv[k].z >> 22) & 2u) | ((bv[k].w >> 23) & 1u);

            // A-half in low 16, B-half in high 16
            uint32_t w = (na << sh) | (nb << (sh + 16));

            // OR across the 4-lane quad: quad_perm [1,0,3,2] then [2,3,0,1]
            w |= (uint32_t)__builtin_amdgcn_mov_dpp((int)w, 0xB1, 0xF, 0xF, true);
            w |= (uint32_t)__builtin_amdgcn_mov_dpp((int)w, 0x4E, 0xF, 0xF, true);

            // fp16 add via exact fp32 add + RNE convert (bit-exact, 24>=2*11+2)
            float fa = __half2float(__ushort_as_half((unsigned short)(w & 0xFFFFu)));
            float fb = __half2float(__ushort_as_half((unsigned short)(w >> 16)));
            uint32_t us = (uint32_t)__half_as_ushort(__float2half_rn(fa + fb));

            // this lane's quarter of the sum, MSB first
            uint32_t ns = (us >> sh) & 0xFu;
            float4 o;
            o.x = (float)((ns >> 3) & 1u);
            o.y = (float)((ns >> 2) & 1u);
            o.z = (float)((ns >> 1) & 1u);
            o.w = (float)( ns       & 1u);

            O[base + k * 64] = o;
        }
    }

    // ---- tail (nf4 % 256 != 0; never taken for the fixed N) ----
    const int tailStart = nChunks << 8;
    if (tailStart < nf4 && wid == nWaves - 1) {
        for (int f4 = tailStart + lane; ; f4 += 64) {
            // nf4 is a multiple of 4 (each row = 4 float4s), so each 4-lane
            // quad passes/fails together and the quad shuffles stay defined.
            if (f4 >= nf4) break;
            uint4 a = A[f4];
            uint4 b = B[f4];
            uint32_t na = ((a.x >> 20) & 8u) | ((a.y >> 21) & 4u) |
                          ((a.z >> 22) & 2u) | ((a.w >> 23) & 1u);
            uint32_t nb = ((b.x >> 20) & 8u) | ((b.y >> 21) & 4u) |
                          ((b.z >> 22) & 2u) | ((b.w >> 23) & 1u);
            uint32_t w = (na << sh) | (nb << (sh + 16));
            w |= (uint32_t)__shfl_xor((int)w, 1);
            w |= (uint32_t)__shfl_xor((int)w, 2);

            float fa = __half2float(__ushort_as_half((unsigned short)(w & 0xFFFFu)));
            float fb = __half2float(__ushort_as_half((unsigned short)(w >> 16)));
            uint32_t us = (uint32_t)__half_as_ushort(__float2half_rn(fa + fb));

            uint32_t ns = (us >> sh) & 0xFu;
            float4 o;
            o.x = (float)((ns >> 3) & 1u);
            o.y = (float)((ns >> 2) & 1u);
            o.z = (float)((ns >> 1) & 1u);
            o.w = (float)( ns       & 1u);
            O[f4] = o;
        }
    }
}

extern "C" void kernel_launch(void* const* d_in, const int* in_sizes, int n_in,
                              void* d_out, int out_size, void* d_ws, size_t ws_size,
                              hipStream_t stream) {
    const uint4* A = (const uint4*)d_in[0];
    const uint4* B = (const uint4*)d_in[1];
    float4* O = (float4*)d_out;

    int nf4 = in_sizes[0] / 4;          // total float4s per input

    // Persistent grid: 2048 blocks * 256 threads = 8192 waves
    //                = 32 waves/CU on 256 CUs (exactly full residency).
    int block = 256;
    int nChunks = nf4 >> 8;
    int grid = 2048;
    if (grid > nChunks && nChunks > 0) grid = nChunks; // tiny-input safety
    if (grid < 1) grid = 1;
    spike_fp16_add_kernel<<<grid, block, 0, stream>>>(A, B, O, nf4);
}

// Round 4
// 580.088 us; speedup vs baseline: 1.0083x; 1.0054x over previous
//
#include <hip/hip_runtime.h>
#include <hip/hip_fp16.h>

// Phase-separated burst-streaming version.
//
// Layout (unchanged): lane L holds quarter (L&3) of a row; every
// global_load/store_dwordx4 is perfectly coalesced (lane i at base+i*16B,
// 1 KiB/wave/instr). Quarter-nibbles OR-combined across each 4-lane quad via
// DPP quad_perm; all 4 lanes redundantly do the fp16 add (VALU ~92% idle)
// and extract their own quarter of the sum.
//
// History: 4x MLP -> null; persistent grid -> null; NT stores -> -5%.
// Effective rate pinned at ~4.0 TB/s (65% of copy ceiling) with no pipe
// saturated => theory: DRAM-side inefficiency from fine-grained (4 KB)
// stream alternation + read/write turnaround across ~24K concurrent streams.
//
// This version: per-wave chunk doubled to 512 float4 and fully
// phase-separated:
//   8x global_load_dwordx4 from A back-to-back  (8 KB sequential burst)
//   8x global_load_dwordx4 from B back-to-back  (8 KB)
//   compute all 8 k-groups
//   8x global_store_dwordx4 to O back-to-back   (8 KB write burst)
// Fewer stream switches per wave, longer same-row DRAM runs, write bursts.

__global__ __launch_bounds__(256) void spike_fp16_add_kernel(
    const uint4* __restrict__ A, const uint4* __restrict__ B,
    float4* __restrict__ O, int nf4)   // nf4 = total float4 count = nrows*4
{
    const int lane   = threadIdx.x & 63;
    const int wid    = (blockIdx.x * blockDim.x + threadIdx.x) >> 6;
    const int nWaves = (gridDim.x * blockDim.x) >> 6;
    const int q      = lane & 3;
    const int sh     = 12 - 4 * q;      // MSB-first nibble position, this quarter

    const int nChunks = nf4 >> 9;       // 512 float4s per wave-chunk
    const int cpw     = (nChunks + nWaves - 1) / nWaves;
    const int c0      = wid * cpw;
    const int c1      = (c0 + cpw < nChunks) ? c0 + cpw : nChunks;

    for (int c = c0; c < c1; ++c) {
        const int base = (c << 9) + lane;

        // ---- phase 1: 8 A-loads back-to-back (8 KB sequential burst) ----
        uint4 a[8];
        #pragma unroll
        for (int k = 0; k < 8; ++k) a[k] = A[base + k * 64];

        // ---- phase 2: 8 B-loads back-to-back ----
        uint4 b[8];
        #pragma unroll
        for (int k = 0; k < 8; ++k) b[k] = B[base + k * 64];

        // ---- phase 3: compute all 8 k-groups ----
        float4 o[8];
        #pragma unroll
        for (int k = 0; k < 8; ++k) {
            // bit 23 distinguishes 1.0f (0x3F800000) from 0.0f — no v_cvt
            uint32_t na = ((a[k].x >> 20) & 8u) | ((a[k].y >> 21) & 4u) |
                          ((a[k].z >> 22) & 2u) | ((a[k].w >> 23) & 1u);
            uint32_t nb = ((b[k].x >> 20) & 8u) | ((b[k].y >> 21) & 4u) |
                          ((b[k].z >> 22) & 2u) | ((b[k].w >> 23) & 1u);

            // A-half in low 16, B-half in high 16
            uint32_t w = (na << sh) | (nb << (sh + 16));

            // OR across the 4-lane quad: quad_perm [1,0,3,2] then [2,3,0,1]
            w |= (uint32_t)__builtin_amdgcn_mov_dpp((int)w, 0xB1, 0xF, 0xF, true);
            w |= (uint32_t)__builtin_amdgcn_mov_dpp((int)w, 0x4E, 0xF, 0xF, true);

            // fp16 add via exact fp32 add + RNE convert (bit-exact, 24>=2*11+2)
            float fa = __half2float(__ushort_as_half((unsigned short)(w & 0xFFFFu)));
            float fb = __half2float(__ushort_as_half((unsigned short)(w >> 16)));
            uint32_t us = (uint32_t)__half_as_ushort(__float2half_rn(fa + fb));

            // this lane's quarter of the sum, MSB first
            uint32_t ns = (us >> sh) & 0xFu;
            o[k].x = (float)((ns >> 3) & 1u);
            o[k].y = (float)((ns >> 2) & 1u);
            o[k].z = (float)((ns >> 1) & 1u);
            o[k].w = (float)( ns       & 1u);
        }

        // ---- phase 4: 8 stores back-to-back (8 KB write burst) ----
        #pragma unroll
        for (int k = 0; k < 8; ++k) O[base + k * 64] = o[k];
    }

    // ---- tail (nf4 % 512 != 0; never taken for the fixed N) ----
    const int tailStart = nChunks << 9;
    if (tailStart < nf4 && wid == nWaves - 1) {
        for (int f4 = tailStart + lane; ; f4 += 64) {
            // nf4 is a multiple of 4 (each row = 4 float4s), so each 4-lane
            // quad passes/fails together and the quad shuffles stay defined.
            if (f4 >= nf4) break;
            uint4 a = A[f4];
            uint4 b = B[f4];
            uint32_t na = ((a.x >> 20) & 8u) | ((a.y >> 21) & 4u) |
                          ((a.z >> 22) & 2u) | ((a.w >> 23) & 1u);
            uint32_t nb = ((b.x >> 20) & 8u) | ((b.y >> 21) & 4u) |
                          ((b.z >> 22) & 2u) | ((b.w >> 23) & 1u);
            uint32_t w = (na << sh) | (nb << (sh + 16));
            w |= (uint32_t)__shfl_xor((int)w, 1);
            w |= (uint32_t)__shfl_xor((int)w, 2);

            float fa = __half2float(__ushort_as_half((unsigned short)(w & 0xFFFFu)));
            float fb = __half2float(__ushort_as_half((unsigned short)(w >> 16)));
            uint32_t us = (uint32_t)__half_as_ushort(__float2half_rn(fa + fb));

            uint32_t ns = (us >> sh) & 0xFu;
            float4 o;
            o.x = (float)((ns >> 3) & 1u);
            o.y = (float)((ns >> 2) & 1u);
            o.z = (float)((ns >> 1) & 1u);
            o.w = (float)( ns       & 1u);
            O[f4] = o;
        }
    }
}

extern "C" void kernel_launch(void* const* d_in, const int* in_sizes, int n_in,
                              void* d_out, int out_size, void* d_ws, size_t ws_size,
                              hipStream_t stream) {
    const uint4* A = (const uint4*)d_in[0];
    const uint4* B = (const uint4*)d_in[1];
    float4* O = (float4*)d_out;

    int nf4 = in_sizes[0] / 4;          // total float4s per input

    // Persistent grid: 2048 blocks * 256 threads = 8192 waves
    //                = 32 waves/CU on 256 CUs (full residency at low VGPR;
    //                  at ~80 VGPR still >= 16 waves/CU, beyond the ~19
    //                  effective waves the memory system was using).
    int block = 256;
    int nChunks = nf4 >> 9;
    int grid = 2048;
    if (grid > nChunks && nChunks > 0) grid = nChunks; // tiny-input safety
    if (grid < 1) grid = 1;
    spike_fp16_add_kernel<<<grid, block, 0, stream>>>(A, B, O, nf4);
}